// Round 1
// baseline (3656.958 us; speedup 1.0000x reference)
//
#include <hip/hip_runtime.h>

typedef __bf16 bf16_t;
typedef __bf16 bf16x8 __attribute__((ext_vector_type(8)));
typedef float f32x4 __attribute__((ext_vector_type(4)));

#define MT 64  // points per block

// ---------- swizzled LDS access (G4: byte ^= (row&7)<<4, conflict-free b128) ----
__device__ __forceinline__ int swz(int row, int colbyte) {
  return row * 512 + (colbyte ^ ((row & 7) << 4));
}
__device__ __forceinline__ void st_act(unsigned short* buf, int row, int col, float v) {
  int b = swz(row, col * 2);
  buf[b >> 1] = __builtin_bit_cast(unsigned short, (bf16_t)v);
}
__device__ __forceinline__ bf16x8 ld_frag(const unsigned short* buf, int row, int kbyte) {
  int b = swz(row, kbyte);
  uint4 u = *reinterpret_cast<const uint4*>(reinterpret_cast<const char*>(buf) + b);
  return __builtin_bit_cast(bf16x8, u);
}

// ---------- one MFMA layer: C(64xN) = act( A(64xK)@W(KxN) + b ) ---------------
// A in LDS (bf16, swizzled); W,b fp32 global; C written to LDS (bf16, swizzled).
// wave handles NCPW n-columns (16 wide each), all 4 m-tiles.
template <int KSTEPS, int NCPW, bool RELU>
__device__ __forceinline__ void mfma_layer(const unsigned short* inb, unsigned short* outb,
                                           const float* __restrict__ Wg,
                                           const float* __restrict__ bg,
                                           int N, int Kmax, int wid, int lane) {
  const int l15 = lane & 15;
  const int lhi = lane >> 4;  // 0..3
#pragma unroll
  for (int t = 0; t < NCPW; ++t) {
    const int nc = wid * NCPW + t;
    const int col = nc * 16 + l15;
    const float bias = bg[col];
    bf16x8 bfrag[KSTEPS];
#pragma unroll
    for (int ks = 0; ks < KSTEPS; ++ks) {
#pragma unroll
      for (int j = 0; j < 8; ++j) {
        const int k = ks * 32 + lhi * 8 + j;
        float wv = (k < Kmax) ? Wg[(size_t)k * N + col] : 0.0f;
        bfrag[ks][j] = (bf16_t)wv;
      }
    }
#pragma unroll
    for (int m = 0; m < 4; ++m) {
      f32x4 acc = {0.f, 0.f, 0.f, 0.f};
#pragma unroll
      for (int ks = 0; ks < KSTEPS; ++ks) {
        bf16x8 a = ld_frag(inb, m * 16 + l15, ks * 64 + lhi * 16);
        acc = __builtin_amdgcn_mfma_f32_16x16x32_bf16(a, bfrag[ks], acc, 0, 0, 0);
      }
      const int r0 = m * 16 + lhi * 4;
#pragma unroll
      for (int i = 0; i < 4; ++i) {
        float v = acc[i] + bias;
        if (RELU) v = fmaxf(v, 0.f);
        st_act(outb, r0 + i, col, v);
      }
    }
  }
}

// ---------- bilinear sample of 8 channels ------------------------------------
template <bool TP>
__device__ __forceinline__ void sample8(const float* __restrict__ pl,
                                        const float* __restrict__ plt, int Hd, int Wd,
                                        float u, float v, int cgrp, float* o) {
  float ix = fminf(fmaxf(u * (float)Wd - 0.5f, 0.f), (float)Wd - 1.f);
  float iy = fminf(fmaxf(v * (float)Hd - 0.5f, 0.f), (float)Hd - 1.f);
  float x0f = floorf(ix), y0f = floorf(iy);
  float wx = ix - x0f, wy = iy - y0f;
  int x0 = (int)x0f, y0 = (int)y0f;
  int x1 = min(x0 + 1, Wd - 1), y1 = min(y0 + 1, Hd - 1);
  float w00 = (1.f - wx) * (1.f - wy), w01 = wx * (1.f - wy);
  float w10 = (1.f - wx) * wy, w11 = wx * wy;
  if (TP) {
    const float4* p00 = reinterpret_cast<const float4*>(plt + ((size_t)y0 * Wd + x0) * 32 + cgrp);
    const float4* p01 = reinterpret_cast<const float4*>(plt + ((size_t)y0 * Wd + x1) * 32 + cgrp);
    const float4* p10 = reinterpret_cast<const float4*>(plt + ((size_t)y1 * Wd + x0) * 32 + cgrp);
    const float4* p11 = reinterpret_cast<const float4*>(plt + ((size_t)y1 * Wd + x1) * 32 + cgrp);
#pragma unroll
    for (int q = 0; q < 2; ++q) {
      float4 a = p00[q], b = p01[q], c = p10[q], d = p11[q];
      o[q * 4 + 0] = a.x * w00 + b.x * w01 + c.x * w10 + d.x * w11;
      o[q * 4 + 1] = a.y * w00 + b.y * w01 + c.y * w10 + d.y * w11;
      o[q * 4 + 2] = a.z * w00 + b.z * w01 + c.z * w10 + d.z * w11;
      o[q * 4 + 3] = a.w * w00 + b.w * w01 + c.w * w10 + d.w * w11;
    }
  } else {
    const size_t HW = (size_t)Hd * Wd;
#pragma unroll
    for (int i = 0; i < 8; ++i) {
      const float* bc = pl + (size_t)(cgrp + i) * HW;
      float a = bc[(size_t)y0 * Wd + x0], b = bc[(size_t)y0 * Wd + x1];
      float c = bc[(size_t)y1 * Wd + x0], d = bc[(size_t)y1 * Wd + x1];
      o[i] = a * w00 + b * w01 + c * w10 + d * w11;
    }
  }
}

// ---------- plane transpose (32,H,W) fp32 -> (H*W,32) fp32 -------------------
__global__ void KPlanes_transpose(const float* __restrict__ src, float* __restrict__ dst, int HW) {
  int s = blockIdx.x * 256 + threadIdx.x;
  if (s >= HW) return;
#pragma unroll
  for (int c = 0; c < 32; ++c) dst[(size_t)s * 32 + c] = src[(size_t)c * HW + s];
}

// ---------- fused main kernel ------------------------------------------------
template <bool TP>
__global__ __launch_bounds__(256) void KPlanes_fused(
    const float* __restrict__ xyt, const float* __restrict__ yx, const float* __restrict__ xt,
    const float* __restrict__ yt, const float* __restrict__ yx_t, const float* __restrict__ xt_t,
    const float* __restrict__ yt_t, const float* __restrict__ fw1, const float* __restrict__ fb1,
    const float* __restrict__ fw2, const float* __restrict__ fb2, const float* __restrict__ w1,
    const float* __restrict__ b1, const float* __restrict__ w2, const float* __restrict__ b2,
    const float* __restrict__ w3, const float* __restrict__ b3, const float* __restrict__ w4,
    const float* __restrict__ b4, const int* __restrict__ fnum_p, float* __restrict__ out) {
  __shared__ unsigned short actA[64 * 256];  // 32 KB
  __shared__ unsigned short actB[64 * 256];  // 32 KB
  const int tid = threadIdx.x;
  const int lane = tid & 63;
  const int wid = tid >> 6;
  const float fnum = (float)(*fnum_p);

  // ---- phase 0: sampling. 4 threads/point, 8 channels each -> feat in actA[.,0:32)
  {
    const int p = tid >> 2;
    const int cgrp = (tid & 3) * 8;
    const int pg = blockIdx.x * MT + p;
    float x = xyt[pg * 3 + 0];
    float y = xyt[pg * 3 + 1];
    float t = xyt[pg * 3 + 2] / fnum;
    float syx[8], sxt[8], syt[8];
    sample8<TP>(yx, yx_t, 540, 960, y, x, cgrp, syx);   // u=y over W=960, v=x over H=540
    sample8<TP>(xt, xt_t, 960, 300, x, t, cgrp, sxt);   // u=x over W=300, v=t over H=960
    sample8<TP>(yt, yt_t, 540, 300, y, t, cgrp, syt);   // u=y over W=300, v=t over H=540
#pragma unroll
    for (int i = 0; i < 8; ++i) st_act(actA, p, cgrp + i, syx[i] * sxt[i] * syt[i]);
  }
  __syncthreads();
  // ---- L1: feat(32) -> h1(64) relu, actA -> actB
  mfma_layer<1, 1, true>(actA, actB, fw1, fb1, 64, 32, wid, lane);
  __syncthreads();
  // ---- L2: h1(64) -> h2(64) relu, actB -> actA[.,0:64)
  mfma_layer<2, 1, true>(actB, actA, fw2, fb2, 64, 64, wid, lane);
  // ---- pos-enc into actA[.,64:119), zeros to 128 (concurrent with L2, disjoint cols)
  if (tid < 64) {
    const int pg = blockIdx.x * MT + tid;
    float px = xyt[pg * 3 + 0];
    float py = xyt[pg * 3 + 1];
    float pt = xyt[pg * 3 + 2] / fnum;
    st_act(actA, tid, 64, py);
    st_act(actA, tid, 65, px);
    float sc = 1.f;
#pragma unroll
    for (int j = 0; j < 10; ++j) {
      st_act(actA, tid, 66 + j * 4 + 0, sinf(sc * py));
      st_act(actA, tid, 66 + j * 4 + 1, sinf(sc * px));
      st_act(actA, tid, 66 + j * 4 + 2, cosf(sc * py));
      st_act(actA, tid, 66 + j * 4 + 3, cosf(sc * px));
      sc *= 2.f;
    }
    st_act(actA, tid, 106, pt);
    sc = 1.f;
#pragma unroll
    for (int j = 0; j < 6; ++j) {
      st_act(actA, tid, 107 + j * 2, sinf(sc * pt));
      st_act(actA, tid, 108 + j * 2, cosf(sc * pt));
      sc *= 2.f;
    }
#pragma unroll
    for (int c = 119; c < 128; ++c) st_act(actA, tid, c, 0.f);
  }
  __syncthreads();
  // ---- L3: full(119, padded 128) -> z1(256) relu, actA -> actB
  mfma_layer<4, 4, true>(actA, actB, w1, b1, 256, 119, wid, lane);
  __syncthreads();
  // ---- L4: z1 -> z2(256) relu, actB -> actA
  mfma_layer<8, 4, true>(actB, actA, w2, b2, 256, 256, wid, lane);
  __syncthreads();
  // ---- L5: z2 -> z3(256) relu, actA -> actB
  mfma_layer<8, 4, true>(actA, actB, w3, b3, 256, 256, wid, lane);
  __syncthreads();
  // ---- L6: z3(256) -> 3, sigmoid, fp32 scalar. thread = (point, channel)
  {
    const int p = tid >> 2, c = tid & 3;
    if (c < 3) {
      float acc = 0.f;
#pragma unroll
      for (int k0 = 0; k0 < 256; k0 += 8) {
        int b = swz(p, k0 * 2);
        uint4 u = *reinterpret_cast<const uint4*>(reinterpret_cast<const char*>(actB) + b);
        bf16x8 z = __builtin_bit_cast(bf16x8, u);
#pragma unroll
        for (int j = 0; j < 8; ++j) acc += (float)z[j] * w4[(k0 + j) * 3 + c];
      }
      acc += b4[c];
      out[(size_t)(blockIdx.x * MT + p) * 3 + c] = 1.f / (1.f + expf(-acc));
    }
  }
}

extern "C" void kernel_launch(void* const* d_in, const int* in_sizes, int n_in, void* d_out,
                              int out_size, void* d_ws, size_t ws_size, hipStream_t stream) {
  const float* xyt = (const float*)d_in[0];
  const float* yx = (const float*)d_in[1];
  const float* xt = (const float*)d_in[2];
  const float* yt = (const float*)d_in[3];
  const float* fw1 = (const float*)d_in[4];
  const float* fb1 = (const float*)d_in[5];
  const float* fw2 = (const float*)d_in[6];
  const float* fb2 = (const float*)d_in[7];
  const float* w1 = (const float*)d_in[8];
  const float* b1 = (const float*)d_in[9];
  const float* w2 = (const float*)d_in[10];
  const float* b2 = (const float*)d_in[11];
  const float* w3 = (const float*)d_in[12];
  const float* b3 = (const float*)d_in[13];
  const float* w4 = (const float*)d_in[14];
  const float* b4 = (const float*)d_in[15];
  const int* fnum = (const int*)d_in[16];
  float* out = (float*)d_out;

  const int hw_yx = 540 * 960, hw_xt = 960 * 300, hw_yt = 540 * 300;
  const size_t need = ((size_t)hw_yx + hw_xt + hw_yt) * 32 * sizeof(float);
  float* ws = (float*)d_ws;
  float* yx_t = ws;
  float* xt_t = yx_t + (size_t)hw_yx * 32;
  float* yt_t = xt_t + (size_t)hw_xt * 32;

  const int nblk = 1048576 / MT;
  if (ws_size >= need) {
    KPlanes_transpose<<<(hw_yx + 255) / 256, 256, 0, stream>>>(yx, yx_t, hw_yx);
    KPlanes_transpose<<<(hw_xt + 255) / 256, 256, 0, stream>>>(xt, xt_t, hw_xt);
    KPlanes_transpose<<<(hw_yt + 255) / 256, 256, 0, stream>>>(yt, yt_t, hw_yt);
    KPlanes_fused<true><<<nblk, 256, 0, stream>>>(xyt, yx, xt, yt, yx_t, xt_t, yt_t, fw1, fb1,
                                                  fw2, fb2, w1, b1, w2, b2, w3, b3, w4, b4, fnum,
                                                  out);
  } else {
    KPlanes_fused<false><<<nblk, 256, 0, stream>>>(xyt, yx, xt, yt, yx_t, xt_t, yt_t, fw1, fb1,
                                                   fw2, fb2, w1, b1, w2, b2, w3, b3, w4, b4, fnum,
                                                   out);
  }
}

// Round 2
// 976.519 us; speedup vs baseline: 3.7449x; 3.7449x over previous
//
#include <hip/hip_runtime.h>

typedef __bf16 bf16_t;
typedef __bf16 bf16x8 __attribute__((ext_vector_type(8)));
typedef unsigned short u16x8 __attribute__((ext_vector_type(8)));
typedef float f32x4 __attribute__((ext_vector_type(4)));

#define MT 128
#define NTHR 512
#define NBLK (1048576 / MT)

// LDS row stride = 256 cols * 2B = 512B. XOR-swizzle 16B slots by row (bijective per row).
__device__ __forceinline__ int swz(int row, int colbyte) {
  return row * 512 + (colbyte ^ ((row & 31) << 4));
}
__device__ __forceinline__ void st_act(unsigned short* buf, int row, int col, float v) {
  buf[swz(row, col * 2) >> 1] = __builtin_bit_cast(unsigned short, (bf16_t)v);
}
__device__ __forceinline__ bf16x8 ld_frag(const unsigned short* buf, int row, int kbyte) {
  const uint4 u =
      *reinterpret_cast<const uint4*>(reinterpret_cast<const char*>(buf) + swz(row, kbyte));
  return __builtin_bit_cast(bf16x8, u);
}

// ---------- pack fp32 weights (K,N) row-major into bf16 MFMA B-fragments -----
// frag f = g*KS + ks; lane holds col = g*16+(lane&15), k = ks*32+(lane>>4)*8+j, j=0..7
__global__ void KPlanes_packw(const float* __restrict__ W, uint4* __restrict__ dst, int N, int K,
                              int KS, int nfrag) {
  const int tid = blockIdx.x * 256 + threadIdx.x;
  const int lane = tid & 63, f = tid >> 6;
  if (f >= nfrag) return;
  const int g = f / KS, ks = f - g * KS;
  const int col = g * 16 + (lane & 15);
  u16x8 v;
#pragma unroll
  for (int j = 0; j < 8; ++j) {
    const int k = ks * 32 + (lane >> 4) * 8 + j;
    const float w = (k < K && col < N) ? W[(size_t)k * N + col] : 0.0f;
    v[j] = __builtin_bit_cast(unsigned short, (bf16_t)w);
  }
  dst[(size_t)f * 64 + lane] = __builtin_bit_cast(uint4, v);
}

// ---------- transpose plane (32,H,W) fp32 -> (H*W,32) fp32 -------------------
__global__ void KPlanes_transpose(const float* __restrict__ src, float* __restrict__ dst, int HW) {
  int s = blockIdx.x * 256 + threadIdx.x;
  if (s >= HW) return;
#pragma unroll
  for (int c = 0; c < 32; ++c) dst[(size_t)s * 32 + c] = src[(size_t)c * HW + s];
}

// ---------- bilinear sample of 8 channels ------------------------------------
template <bool TP>
__device__ __forceinline__ void sample8(const float* __restrict__ pl,
                                        const float* __restrict__ plt, int Hd, int Wd, float u,
                                        float v, int cgrp, float* o) {
  float ix = fminf(fmaxf(u * (float)Wd - 0.5f, 0.f), (float)Wd - 1.f);
  float iy = fminf(fmaxf(v * (float)Hd - 0.5f, 0.f), (float)Hd - 1.f);
  float x0f = floorf(ix), y0f = floorf(iy);
  float wx = ix - x0f, wy = iy - y0f;
  int x0 = (int)x0f, y0 = (int)y0f;
  int x1 = min(x0 + 1, Wd - 1), y1 = min(y0 + 1, Hd - 1);
  float w00 = (1.f - wx) * (1.f - wy), w01 = wx * (1.f - wy);
  float w10 = (1.f - wx) * wy, w11 = wx * wy;
  if (TP) {
    const float4* p00 = reinterpret_cast<const float4*>(plt + ((size_t)y0 * Wd + x0) * 32 + cgrp);
    const float4* p01 = reinterpret_cast<const float4*>(plt + ((size_t)y0 * Wd + x1) * 32 + cgrp);
    const float4* p10 = reinterpret_cast<const float4*>(plt + ((size_t)y1 * Wd + x0) * 32 + cgrp);
    const float4* p11 = reinterpret_cast<const float4*>(plt + ((size_t)y1 * Wd + x1) * 32 + cgrp);
#pragma unroll
    for (int q = 0; q < 2; ++q) {
      float4 a = p00[q], b = p01[q], c = p10[q], d = p11[q];
      o[q * 4 + 0] = a.x * w00 + b.x * w01 + c.x * w10 + d.x * w11;
      o[q * 4 + 1] = a.y * w00 + b.y * w01 + c.y * w10 + d.y * w11;
      o[q * 4 + 2] = a.z * w00 + b.z * w01 + c.z * w10 + d.z * w11;
      o[q * 4 + 3] = a.w * w00 + b.w * w01 + c.w * w10 + d.w * w11;
    }
  } else {
    const size_t HW = (size_t)Hd * Wd;
#pragma unroll
    for (int i = 0; i < 8; ++i) {
      const float* bc = pl + (size_t)(cgrp + i) * HW;
      float a = bc[(size_t)y0 * Wd + x0], b = bc[(size_t)y0 * Wd + x1];
      float c = bc[(size_t)y1 * Wd + x0], d = bc[(size_t)y1 * Wd + x1];
      o[i] = a * w00 + b * w01 + c * w10 + d * w11;
    }
  }
}

// ---------- MFMA layer, prepacked bf16 weights, A-frag reuse across NCPW ------
template <int KS, int NCPW, int MTPW, bool RELU>
__device__ __forceinline__ void layer2(const unsigned short* inb, unsigned short* outb,
                                       const uint4* __restrict__ Wf, const float* __restrict__ bg,
                                       int gbase, int moff, int lane) {
  const int l15 = lane & 15, lhi = lane >> 4;
  bf16x8 bf[NCPW][KS];
  float bias[NCPW];
#pragma unroll
  for (int t = 0; t < NCPW; ++t) {
    const int g = gbase + t;
    bias[t] = bg[g * 16 + l15];
#pragma unroll
    for (int ks = 0; ks < KS; ++ks)
      bf[t][ks] = __builtin_bit_cast(bf16x8, Wf[(size_t)(g * KS + ks) * 64 + lane]);
  }
#pragma unroll
  for (int m = 0; m < MTPW; ++m) {
    const int mr = (moff + m) * 16;
    f32x4 acc[NCPW];
#pragma unroll
    for (int t = 0; t < NCPW; ++t) acc[t] = f32x4{0.f, 0.f, 0.f, 0.f};
#pragma unroll
    for (int ks = 0; ks < KS; ++ks) {
      const bf16x8 a = ld_frag(inb, mr + l15, ks * 64 + lhi * 16);
#pragma unroll
      for (int t = 0; t < NCPW; ++t)
        acc[t] = __builtin_amdgcn_mfma_f32_16x16x32_bf16(a, bf[t][ks], acc[t], 0, 0, 0);
    }
#pragma unroll
    for (int t = 0; t < NCPW; ++t) {
      const int col = (gbase + t) * 16 + l15;
      const int r0 = mr + lhi * 4;
#pragma unroll
      for (int i = 0; i < 4; ++i) {
        float v = acc[t][i] + bias[t];
        if (RELU) v = fmaxf(v, 0.f);
        st_act(outb, r0 + i, col, v);
      }
    }
  }
}

// ---------- main fused kernel: 128 points/block, 8 waves ----------------------
__global__ __launch_bounds__(NTHR) void KPlanes_fused2(
    const float* __restrict__ xyt, const float* __restrict__ yx_t, const float* __restrict__ xt_t,
    const float* __restrict__ yt_t, const uint4* __restrict__ wf1, const float* __restrict__ fb1,
    const uint4* __restrict__ wf2, const float* __restrict__ fb2, const uint4* __restrict__ wf3,
    const float* __restrict__ b1, const uint4* __restrict__ wf4, const float* __restrict__ b2,
    const uint4* __restrict__ wf5, const float* __restrict__ b3, const uint4* __restrict__ wf6,
    const float* __restrict__ b4, const int* __restrict__ fnum_p, float* __restrict__ out) {
  __shared__ unsigned short actA[MT * 256];  // 64 KB
  __shared__ unsigned short actB[MT * 256];  // 64 KB
  const int tid = threadIdx.x;
  const int lane = tid & 63;
  const int wid = tid >> 6;
  const float fnum = (float)(*fnum_p);

  // ---- phase 0: sampling (4 thr/point, 8 ch each) + pos-enc, all into actA
  {
    const int p = tid >> 2;
    const int q = tid & 3;
    const int cgrp = q * 8;
    const int pg = blockIdx.x * MT + p;
    const float x = xyt[pg * 3 + 0];
    const float y = xyt[pg * 3 + 1];
    const float t = xyt[pg * 3 + 2] / fnum;
    float syx[8], sxt[8], syt[8];
    sample8<true>(nullptr, yx_t, 540, 960, y, x, cgrp, syx);
    sample8<true>(nullptr, xt_t, 960, 300, x, t, cgrp, sxt);
    sample8<true>(nullptr, yt_t, 540, 300, y, t, cgrp, syt);
#pragma unroll
    for (int i = 0; i < 8; ++i) st_act(actA, p, cgrp + i, syx[i] * sxt[i] * syt[i]);
    // pos-enc cols 64..118, zero-pad 119..127 (disjoint from feat cols 0..31)
    if (q == 0) {
      st_act(actA, p, 64, y);
      st_act(actA, p, 65, x);
#pragma unroll
      for (int j = 0; j < 5; ++j) {
        const float sc = (float)(1 << j);
        float sy, cy, sx, cx;
        sincosf(sc * y, &sy, &cy);
        sincosf(sc * x, &sx, &cx);
        st_act(actA, p, 66 + j * 4 + 0, sy);
        st_act(actA, p, 66 + j * 4 + 1, sx);
        st_act(actA, p, 66 + j * 4 + 2, cy);
        st_act(actA, p, 66 + j * 4 + 3, cx);
      }
    } else if (q == 1) {
#pragma unroll
      for (int j = 5; j < 10; ++j) {
        const float sc = (float)(1 << j);
        float sy, cy, sx, cx;
        sincosf(sc * y, &sy, &cy);
        sincosf(sc * x, &sx, &cx);
        st_act(actA, p, 66 + j * 4 + 0, sy);
        st_act(actA, p, 66 + j * 4 + 1, sx);
        st_act(actA, p, 66 + j * 4 + 2, cy);
        st_act(actA, p, 66 + j * 4 + 3, cx);
      }
    } else if (q == 2) {
      st_act(actA, p, 106, t);
      float sc = 1.f;
#pragma unroll
      for (int j = 0; j < 6; ++j) {
        float st_, ct_;
        sincosf(sc * t, &st_, &ct_);
        st_act(actA, p, 107 + j * 2, st_);
        st_act(actA, p, 108 + j * 2, ct_);
        sc *= 2.f;
      }
#pragma unroll
      for (int c = 119; c < 128; ++c) st_act(actA, p, c, 0.f);
    }
  }
  __syncthreads();
  // L1: feat(32)->h1(64). waves: colgroup=wid&3, m-half=wid>>2
  layer2<1, 1, 4, true>(actA, actB, wf1, fb1, wid & 3, (wid >> 2) * 4, lane);
  __syncthreads();
  // L2: h1(64)->h2(64) into actA cols 0..63 (pe cols 64..127 untouched)
  layer2<2, 1, 4, true>(actB, actA, wf2, fb2, wid & 3, (wid >> 2) * 4, lane);
  __syncthreads();
  // L3: full(119 pad 128)->z1(256)
  layer2<4, 2, 8, true>(actA, actB, wf3, b1, wid * 2, 0, lane);
  __syncthreads();
  // L4: z1->z2(256)
  layer2<8, 2, 8, true>(actB, actA, wf4, b2, wid * 2, 0, lane);
  __syncthreads();
  // L5: z2->z3(256)
  layer2<8, 2, 8, true>(actA, actB, wf5, b3, wid * 2, 0, lane);
  __syncthreads();
  // L6: z3(256)->3 (N padded to 16), sigmoid, global store. wave wid owns m-tile wid.
  {
    const int l15 = lane & 15, lhi = lane >> 4;
    bf16x8 bf6[8];
#pragma unroll
    for (int ks = 0; ks < 8; ++ks) bf6[ks] = __builtin_bit_cast(bf16x8, wf6[ks * 64 + lane]);
    const int mr = wid * 16;
    f32x4 acc = {0.f, 0.f, 0.f, 0.f};
#pragma unroll
    for (int ks = 0; ks < 8; ++ks)
      acc = __builtin_amdgcn_mfma_f32_16x16x32_bf16(ld_frag(actB, mr + l15, ks * 64 + lhi * 16),
                                                    bf6[ks], acc, 0, 0, 0);
    if (l15 < 3) {
      const float bb = b4[l15];
#pragma unroll
      for (int i = 0; i < 4; ++i) {
        const float v = acc[i] + bb;
        out[((size_t)blockIdx.x * MT + mr + lhi * 4 + i) * 3 + l15] = 1.f / (1.f + expf(-v));
      }
    }
  }
}

// ================= fallback (round-1 proven path, global fp32 weights) ========
template <int KSTEPS, int NCPW, bool RELU>
__device__ __forceinline__ void mfma_layer_fb(const unsigned short* inb, unsigned short* outb,
                                              const float* __restrict__ Wg,
                                              const float* __restrict__ bg, int N, int Kmax,
                                              int wid, int lane) {
  const int l15 = lane & 15;
  const int lhi = lane >> 4;
#pragma unroll
  for (int t = 0; t < NCPW; ++t) {
    const int nc = wid * NCPW + t;
    const int col = nc * 16 + l15;
    const float bias = bg[col];
    bf16x8 bfrag[KSTEPS];
#pragma unroll
    for (int ks = 0; ks < KSTEPS; ++ks) {
#pragma unroll
      for (int j = 0; j < 8; ++j) {
        const int k = ks * 32 + lhi * 8 + j;
        float wv = (k < Kmax) ? Wg[(size_t)k * N + col] : 0.0f;
        bfrag[ks][j] = (bf16_t)wv;
      }
    }
#pragma unroll
    for (int m = 0; m < 4; ++m) {
      f32x4 acc = {0.f, 0.f, 0.f, 0.f};
#pragma unroll
      for (int ks = 0; ks < KSTEPS; ++ks) {
        bf16x8 a = ld_frag(inb, m * 16 + l15, ks * 64 + lhi * 16);
        acc = __builtin_amdgcn_mfma_f32_16x16x32_bf16(a, bfrag[ks], acc, 0, 0, 0);
      }
      const int r0 = m * 16 + lhi * 4;
#pragma unroll
      for (int i = 0; i < 4; ++i) {
        float v = acc[i] + bias;
        if (RELU) v = fmaxf(v, 0.f);
        st_act(outb, r0 + i, col, v);
      }
    }
  }
}

__global__ __launch_bounds__(256) void KPlanes_fused_fb(
    const float* __restrict__ xyt, const float* __restrict__ yx, const float* __restrict__ xt,
    const float* __restrict__ yt, const float* __restrict__ fw1, const float* __restrict__ fb1,
    const float* __restrict__ fw2, const float* __restrict__ fb2, const float* __restrict__ w1,
    const float* __restrict__ b1, const float* __restrict__ w2, const float* __restrict__ b2,
    const float* __restrict__ w3, const float* __restrict__ b3, const float* __restrict__ w4,
    const float* __restrict__ b4, const int* __restrict__ fnum_p, float* __restrict__ out) {
  __shared__ unsigned short actA[64 * 256];
  __shared__ unsigned short actB[64 * 256];
  const int tid = threadIdx.x;
  const int lane = tid & 63;
  const int wid = tid >> 6;
  const float fnum = (float)(*fnum_p);
  {
    const int p = tid >> 2;
    const int cgrp = (tid & 3) * 8;
    const int pg = blockIdx.x * 64 + p;
    float x = xyt[pg * 3 + 0];
    float y = xyt[pg * 3 + 1];
    float t = xyt[pg * 3 + 2] / fnum;
    float syx[8], sxt[8], syt[8];
    sample8<false>(yx, nullptr, 540, 960, y, x, cgrp, syx);
    sample8<false>(xt, nullptr, 960, 300, x, t, cgrp, sxt);
    sample8<false>(yt, nullptr, 540, 300, y, t, cgrp, syt);
#pragma unroll
    for (int i = 0; i < 8; ++i) st_act(actA, p, cgrp + i, syx[i] * sxt[i] * syt[i]);
  }
  __syncthreads();
  mfma_layer_fb<1, 1, true>(actA, actB, fw1, fb1, 64, 32, wid, lane);
  __syncthreads();
  mfma_layer_fb<2, 1, true>(actB, actA, fw2, fb2, 64, 64, wid, lane);
  if (tid < 64) {
    const int pg = blockIdx.x * 64 + tid;
    float px = xyt[pg * 3 + 0];
    float py = xyt[pg * 3 + 1];
    float pt = xyt[pg * 3 + 2] / fnum;
    st_act(actA, tid, 64, py);
    st_act(actA, tid, 65, px);
    float sc = 1.f;
#pragma unroll
    for (int j = 0; j < 10; ++j) {
      st_act(actA, tid, 66 + j * 4 + 0, sinf(sc * py));
      st_act(actA, tid, 66 + j * 4 + 1, sinf(sc * px));
      st_act(actA, tid, 66 + j * 4 + 2, cosf(sc * py));
      st_act(actA, tid, 66 + j * 4 + 3, cosf(sc * px));
      sc *= 2.f;
    }
    st_act(actA, tid, 106, pt);
    sc = 1.f;
#pragma unroll
    for (int j = 0; j < 6; ++j) {
      st_act(actA, tid, 107 + j * 2, sinf(sc * pt));
      st_act(actA, tid, 108 + j * 2, cosf(sc * pt));
      sc *= 2.f;
    }
#pragma unroll
    for (int c = 119; c < 128; ++c) st_act(actA, tid, c, 0.f);
  }
  __syncthreads();
  mfma_layer_fb<4, 4, true>(actA, actB, w1, b1, 256, 119, wid, lane);
  __syncthreads();
  mfma_layer_fb<8, 4, true>(actB, actA, w2, b2, 256, 256, wid, lane);
  __syncthreads();
  mfma_layer_fb<8, 4, true>(actA, actB, w3, b3, 256, 256, wid, lane);
  __syncthreads();
  {
    const int p = tid >> 2, c = tid & 3;
    if (c < 3) {
      float acc = 0.f;
#pragma unroll
      for (int k0 = 0; k0 < 256; k0 += 8) {
        int b = swz(p, k0 * 2);
        uint4 u = *reinterpret_cast<const uint4*>(reinterpret_cast<const char*>(actB) + b);
        bf16x8 z = __builtin_bit_cast(bf16x8, u);
#pragma unroll
        for (int j = 0; j < 8; ++j) acc += (float)z[j] * w4[(k0 + j) * 3 + c];
      }
      acc += b4[c];
      out[(size_t)(blockIdx.x * 64 + p) * 3 + c] = 1.f / (1.f + expf(-acc));
    }
  }
}

extern "C" void kernel_launch(void* const* d_in, const int* in_sizes, int n_in, void* d_out,
                              int out_size, void* d_ws, size_t ws_size, hipStream_t stream) {
  const float* xyt = (const float*)d_in[0];
  const float* yx = (const float*)d_in[1];
  const float* xt = (const float*)d_in[2];
  const float* yt = (const float*)d_in[3];
  const float* fw1 = (const float*)d_in[4];
  const float* fb1 = (const float*)d_in[5];
  const float* fw2 = (const float*)d_in[6];
  const float* fb2 = (const float*)d_in[7];
  const float* w1 = (const float*)d_in[8];
  const float* b1 = (const float*)d_in[9];
  const float* w2 = (const float*)d_in[10];
  const float* b2 = (const float*)d_in[11];
  const float* w3 = (const float*)d_in[12];
  const float* b3 = (const float*)d_in[13];
  const float* w4 = (const float*)d_in[14];
  const float* b4 = (const float*)d_in[15];
  const int* fnum = (const int*)d_in[16];
  float* out = (float*)d_out;

  const int hw_yx = 540 * 960, hw_xt = 960 * 300, hw_yt = 540 * 300;
  const size_t plane_bytes = ((size_t)hw_yx + hw_xt + hw_yt) * 32 * sizeof(float);
  const size_t wfrag_bytes = (size_t)340 * 64 * sizeof(uint4);  // 340 frags
  const size_t need = plane_bytes + wfrag_bytes;

  float* yx_t = (float*)d_ws;
  float* xt_t = yx_t + (size_t)hw_yx * 32;
  float* yt_t = xt_t + (size_t)hw_xt * 32;
  uint4* wbase = (uint4*)((char*)d_ws + plane_bytes);
  uint4* wf1 = wbase + 0 * 64;
  uint4* wf2 = wbase + 4 * 64;
  uint4* wf3 = wbase + 12 * 64;
  uint4* wf4 = wbase + 76 * 64;
  uint4* wf5 = wbase + 204 * 64;
  uint4* wf6 = wbase + 332 * 64;

  if (ws_size >= need) {
    KPlanes_transpose<<<(hw_yx + 255) / 256, 256, 0, stream>>>(yx, yx_t, hw_yx);
    KPlanes_transpose<<<(hw_xt + 255) / 256, 256, 0, stream>>>(xt, xt_t, hw_xt);
    KPlanes_transpose<<<(hw_yt + 255) / 256, 256, 0, stream>>>(yt, yt_t, hw_yt);
    KPlanes_packw<<<1, 256, 0, stream>>>(fw1, wf1, 64, 32, 1, 4);
    KPlanes_packw<<<2, 256, 0, stream>>>(fw2, wf2, 64, 64, 2, 8);
    KPlanes_packw<<<16, 256, 0, stream>>>(w1, wf3, 256, 119, 4, 64);
    KPlanes_packw<<<32, 256, 0, stream>>>(w2, wf4, 256, 256, 8, 128);
    KPlanes_packw<<<32, 256, 0, stream>>>(w3, wf5, 256, 256, 8, 128);
    KPlanes_packw<<<2, 256, 0, stream>>>(w4, wf6, 3, 256, 8, 8);
    KPlanes_fused2<<<NBLK, NTHR, 0, stream>>>(xyt, yx_t, xt_t, yt_t, wf1, fb1, wf2, fb2, wf3, b1,
                                              wf4, b2, wf5, b3, wf6, b4, fnum, out);
  } else {
    KPlanes_fused_fb<<<1048576 / 64, 256, 0, stream>>>(xyt, yx, xt, yt, fw1, fb1, fw2, fb2, w1,
                                                       b1, w2, b2, w3, b3, w4, b4, fnum, out);
  }
}

// Round 3
// 681.978 us; speedup vs baseline: 5.3623x; 1.4319x over previous
//
#include <hip/hip_runtime.h>

typedef __bf16 bf16_t;
typedef __bf16 bf16x8 __attribute__((ext_vector_type(8)));
typedef _Float16 f16x8 __attribute__((ext_vector_type(8)));
typedef unsigned short u16x8 __attribute__((ext_vector_type(8)));
typedef float f32x4 __attribute__((ext_vector_type(4)));

#define MT 128
#define NTHR 512
#define NBLK (1048576 / MT)

// LDS row stride = 256 cols * 2B = 512B. XOR-swizzle 16B slots by row.
__device__ __forceinline__ int swz(int row, int colbyte) {
  return row * 512 + (colbyte ^ ((row & 31) << 4));
}
__device__ __forceinline__ void st_act(unsigned short* buf, int row, int col, float v) {
  buf[swz(row, col * 2) >> 1] = __builtin_bit_cast(unsigned short, (bf16_t)v);
}
__device__ __forceinline__ bf16x8 ld_frag(const unsigned short* buf, int row, int kbyte) {
  const uint4 u =
      *reinterpret_cast<const uint4*>(reinterpret_cast<const char*>(buf) + swz(row, kbyte));
  return __builtin_bit_cast(bf16x8, u);
}

// ---------- prologue 1: transpose all 3 planes (32,H,W) fp32 -> (H*W,32) fp16 --
__global__ void KPlanes_tr3(const float* __restrict__ yx, const float* __restrict__ xt,
                            const float* __restrict__ yt, uint4* __restrict__ d0,
                            uint4* __restrict__ d1, uint4* __restrict__ d2) {
  const int HW0 = 518400, HW1 = 288000, HW2 = 162000;
  const int NB0 = 2025, NB1 = 1125;
  const int b = blockIdx.x;
  const float* src;
  uint4* dst;
  int HW, s;
  if (b < NB0) {
    src = yx; dst = d0; HW = HW0; s = b * 256 + threadIdx.x;
  } else if (b < NB0 + NB1) {
    src = xt; dst = d1; HW = HW1; s = (b - NB0) * 256 + threadIdx.x;
  } else {
    src = yt; dst = d2; HW = HW2; s = (b - NB0 - NB1) * 256 + threadIdx.x;
  }
  if (s >= HW) return;
#pragma unroll
  for (int g = 0; g < 4; ++g) {
    u16x8 v;
#pragma unroll
    for (int j = 0; j < 8; ++j) {
      const float w = src[(size_t)(g * 8 + j) * HW + s];
      v[j] = __builtin_bit_cast(unsigned short, (_Float16)w);
    }
    dst[(size_t)s * 4 + g] = __builtin_bit_cast(uint4, v);
  }
}

// ---------- prologue 2: pack ALL fp32 weights into bf16 MFMA B-fragments ------
// frag layout: lane holds col=g*16+(lane&15), k=ks*32+(lane>>4)*8+j
__global__ void KPlanes_packall(const float* __restrict__ fw1, const float* __restrict__ fw2,
                                const float* __restrict__ w1, const float* __restrict__ w2,
                                const float* __restrict__ w3, const float* __restrict__ w4,
                                uint4* __restrict__ dst) {
  const int F = blockIdx.x * 4 + (threadIdx.x >> 6);
  const int lane = threadIdx.x & 63;
  if (F >= 340) return;
  const float* W;
  int N, K, KS, fbase;
  if (F < 4)        { W = fw1; N = 64;  K = 32;  KS = 1; fbase = 0; }
  else if (F < 12)  { W = fw2; N = 64;  K = 64;  KS = 2; fbase = 4; }
  else if (F < 76)  { W = w1;  N = 256; K = 119; KS = 4; fbase = 12; }
  else if (F < 204) { W = w2;  N = 256; K = 256; KS = 8; fbase = 76; }
  else if (F < 332) { W = w3;  N = 256; K = 256; KS = 8; fbase = 204; }
  else              { W = w4;  N = 3;   K = 256; KS = 8; fbase = 332; }
  const int f = F - fbase;
  const int g = f / KS, ks = f - g * KS;
  const int col = g * 16 + (lane & 15);
  u16x8 v;
#pragma unroll
  for (int j = 0; j < 8; ++j) {
    const int k = ks * 32 + (lane >> 4) * 8 + j;
    const float w = (k < K && col < N) ? W[(size_t)k * N + col] : 0.0f;
    v[j] = __builtin_bit_cast(unsigned short, (bf16_t)w);
  }
  dst[(size_t)F * 64 + lane] = __builtin_bit_cast(uint4, v);
}

// ---------- fp16 bilinear sample: load phase + combine phase ------------------
struct Smp {
  uint4 c00, c01, c10, c11;
  float w00, w01, w10, w11;
};
__device__ __forceinline__ Smp sample_ld(const uint4* __restrict__ plt, int Hd, int Wd, float u,
                                         float v, int q) {
  Smp s;
  float ix = fminf(fmaxf(u * (float)Wd - 0.5f, 0.f), (float)Wd - 1.f);
  float iy = fminf(fmaxf(v * (float)Hd - 0.5f, 0.f), (float)Hd - 1.f);
  float x0f = floorf(ix), y0f = floorf(iy);
  float wx = ix - x0f, wy = iy - y0f;
  int x0 = (int)x0f, y0 = (int)y0f;
  int x1 = min(x0 + 1, Wd - 1), y1 = min(y0 + 1, Hd - 1);
  s.w00 = (1.f - wx) * (1.f - wy);
  s.w01 = wx * (1.f - wy);
  s.w10 = (1.f - wx) * wy;
  s.w11 = wx * wy;
  const size_t r0 = (size_t)y0 * Wd, r1 = (size_t)y1 * Wd;
  s.c00 = plt[(r0 + x0) * 4 + q];
  s.c01 = plt[(r0 + x1) * 4 + q];
  s.c10 = plt[(r1 + x0) * 4 + q];
  s.c11 = plt[(r1 + x1) * 4 + q];
  return s;
}
__device__ __forceinline__ void smp_combine(const Smp& s, float* o) {
  const f16x8 a = __builtin_bit_cast(f16x8, s.c00);
  const f16x8 b = __builtin_bit_cast(f16x8, s.c01);
  const f16x8 c = __builtin_bit_cast(f16x8, s.c10);
  const f16x8 d = __builtin_bit_cast(f16x8, s.c11);
#pragma unroll
  for (int i = 0; i < 8; ++i)
    o[i] = (float)a[i] * s.w00 + (float)b[i] * s.w01 + (float)c[i] * s.w10 + (float)d[i] * s.w11;
}

// ---------- MFMA layer, prepacked bf16 weights, A-frag reuse ------------------
template <int KS, int NCPW, int MTPW, bool RELU>
__device__ __forceinline__ void layer2(const unsigned short* inb, unsigned short* outb,
                                       const uint4* __restrict__ Wf, const float* __restrict__ bg,
                                       int gbase, int moff, int lane) {
  const int l15 = lane & 15, lhi = lane >> 4;
  bf16x8 bf[NCPW][KS];
  float bias[NCPW];
#pragma unroll
  for (int t = 0; t < NCPW; ++t) {
    const int g = gbase + t;
    bias[t] = bg[g * 16 + l15];
#pragma unroll
    for (int ks = 0; ks < KS; ++ks)
      bf[t][ks] = __builtin_bit_cast(bf16x8, Wf[(size_t)(g * KS + ks) * 64 + lane]);
  }
#pragma unroll
  for (int m = 0; m < MTPW; ++m) {
    const int mr = (moff + m) * 16;
    f32x4 acc[NCPW];
#pragma unroll
    for (int t = 0; t < NCPW; ++t) acc[t] = f32x4{0.f, 0.f, 0.f, 0.f};
#pragma unroll
    for (int ks = 0; ks < KS; ++ks) {
      const bf16x8 a = ld_frag(inb, mr + l15, ks * 64 + lhi * 16);
#pragma unroll
      for (int t = 0; t < NCPW; ++t)
        acc[t] = __builtin_amdgcn_mfma_f32_16x16x32_bf16(a, bf[t][ks], acc[t], 0, 0, 0);
    }
#pragma unroll
    for (int t = 0; t < NCPW; ++t) {
      const int col = (gbase + t) * 16 + l15;
      const int r0 = mr + lhi * 4;
#pragma unroll
      for (int i = 0; i < 4; ++i) {
        float v = acc[t][i] + bias[t];
        if (RELU) v = fmaxf(v, 0.f);
        st_act(outb, r0 + i, col, v);
      }
    }
  }
}

// ---------- main fused kernel: 128 points/block, 8 waves ----------------------
__global__ __launch_bounds__(NTHR) void KPlanes_fused3(
    const float* __restrict__ xyt, const uint4* __restrict__ yx_h, const uint4* __restrict__ xt_h,
    const uint4* __restrict__ yt_h, const uint4* __restrict__ wf1, const float* __restrict__ fb1,
    const uint4* __restrict__ wf2, const float* __restrict__ fb2, const uint4* __restrict__ wf3,
    const float* __restrict__ b1, const uint4* __restrict__ wf4, const float* __restrict__ b2,
    const uint4* __restrict__ wf5, const float* __restrict__ b3, const uint4* __restrict__ wf6,
    const float* __restrict__ b4, const int* __restrict__ fnum_p, float* __restrict__ out) {
  __shared__ unsigned short actA[MT * 256];  // 64 KB
  __shared__ unsigned short actB[MT * 256];  // 64 KB
  const int tid = threadIdx.x;
  const int lane = tid & 63;
  const int wid = tid >> 6;
  const float fnum = (float)(*fnum_p);

  // ---- phase 0: issue 12 gather loads, overlap pos-enc ALU, combine, store
  {
    const int p = tid >> 2;
    const int q = tid & 3;
    const int pg = blockIdx.x * MT + p;
    const float x = xyt[pg * 3 + 0];
    const float y = xyt[pg * 3 + 1];
    const float t = xyt[pg * 3 + 2] / fnum;
    // issue all corner loads first (12 x dwordx4, in flight during pos-enc)
    Smp sYX = sample_ld(yx_h, 540, 960, y, x, q);
    Smp sXT = sample_ld(xt_h, 960, 300, x, t, q);
    Smp sYT = sample_ld(yt_h, 540, 300, y, t, q);
    // pos-enc via one sincosf + double-angle recurrence per chain
    if (q < 2) {
      const float base = q ? x : y;
      st_act(actA, p, 64 + q, base);
      float sj, cj;
      sincosf(base, &sj, &cj);
#pragma unroll
      for (int j = 0; j < 10; ++j) {
        st_act(actA, p, 66 + j * 4 + q, sj);
        st_act(actA, p, 68 + j * 4 + q, cj);
        const float ns = 2.f * sj * cj;
        cj = fmaf(-2.f * sj, sj, 1.f);
        sj = ns;
      }
    } else if (q == 2) {
      st_act(actA, p, 106, t);
      float sj, cj;
      sincosf(t, &sj, &cj);
#pragma unroll
      for (int j = 0; j < 6; ++j) {
        st_act(actA, p, 107 + 2 * j, sj);
        st_act(actA, p, 108 + 2 * j, cj);
        const float ns = 2.f * sj * cj;
        cj = fmaf(-2.f * sj, sj, 1.f);
        sj = ns;
      }
    } else {
#pragma unroll
      for (int cc = 119; cc < 128; ++cc) st_act(actA, p, cc, 0.f);
    }
    float a8[8], b8[8], c8[8];
    smp_combine(sYX, a8);
    smp_combine(sXT, b8);
    smp_combine(sYT, c8);
#pragma unroll
    for (int i = 0; i < 8; ++i) st_act(actA, p, q * 8 + i, a8[i] * b8[i] * c8[i]);
  }
  __syncthreads();
  // L1: feat(32)->h1(64)
  layer2<1, 1, 4, true>(actA, actB, wf1, fb1, wid & 3, (wid >> 2) * 4, lane);
  __syncthreads();
  // L2: h1(64)->h2(64) into actA cols 0..63 (pos-enc cols 64..127 untouched)
  layer2<2, 1, 4, true>(actB, actA, wf2, fb2, wid & 3, (wid >> 2) * 4, lane);
  __syncthreads();
  // L3: full(119 pad 128)->z1(256)
  layer2<4, 2, 8, true>(actA, actB, wf3, b1, wid * 2, 0, lane);
  __syncthreads();
  // L4: z1->z2(256)
  layer2<8, 2, 8, true>(actB, actA, wf4, b2, wid * 2, 0, lane);
  __syncthreads();
  // L5: z2->z3(256)
  layer2<8, 2, 8, true>(actA, actB, wf5, b3, wid * 2, 0, lane);
  __syncthreads();
  // L6: z3(256)->3 (N padded to 16), sigmoid, store
  {
    const int l15 = lane & 15, lhi = lane >> 4;
    bf16x8 bf6[8];
#pragma unroll
    for (int ks = 0; ks < 8; ++ks) bf6[ks] = __builtin_bit_cast(bf16x8, wf6[ks * 64 + lane]);
    const int mr = wid * 16;
    f32x4 acc = {0.f, 0.f, 0.f, 0.f};
#pragma unroll
    for (int ks = 0; ks < 8; ++ks)
      acc = __builtin_amdgcn_mfma_f32_16x16x32_bf16(ld_frag(actB, mr + l15, ks * 64 + lhi * 16),
                                                    bf6[ks], acc, 0, 0, 0);
    if (l15 < 3) {
      const float bb = b4[l15];
#pragma unroll
      for (int i = 0; i < 4; ++i) {
        const float v = acc[i] + bb;
        out[((size_t)blockIdx.x * MT + mr + lhi * 4 + i) * 3 + l15] = 1.f / (1.f + expf(-v));
      }
    }
  }
}

// ================= fallback (fp32 weights, direct plane sampling) =============
__device__ __forceinline__ void sample8_f(const float* __restrict__ pl, int Hd, int Wd, float u,
                                          float v, int cgrp, float* o) {
  float ix = fminf(fmaxf(u * (float)Wd - 0.5f, 0.f), (float)Wd - 1.f);
  float iy = fminf(fmaxf(v * (float)Hd - 0.5f, 0.f), (float)Hd - 1.f);
  float x0f = floorf(ix), y0f = floorf(iy);
  float wx = ix - x0f, wy = iy - y0f;
  int x0 = (int)x0f, y0 = (int)y0f;
  int x1 = min(x0 + 1, Wd - 1), y1 = min(y0 + 1, Hd - 1);
  float w00 = (1.f - wx) * (1.f - wy), w01 = wx * (1.f - wy);
  float w10 = (1.f - wx) * wy, w11 = wx * wy;
  const size_t HW = (size_t)Hd * Wd;
#pragma unroll
  for (int i = 0; i < 8; ++i) {
    const float* bc = pl + (size_t)(cgrp + i) * HW;
    float a = bc[(size_t)y0 * Wd + x0], b = bc[(size_t)y0 * Wd + x1];
    float c = bc[(size_t)y1 * Wd + x0], d = bc[(size_t)y1 * Wd + x1];
    o[i] = a * w00 + b * w01 + c * w10 + d * w11;
  }
}

template <int KSTEPS, int NCPW, bool RELU>
__device__ __forceinline__ void mfma_layer_fb(const unsigned short* inb, unsigned short* outb,
                                              const float* __restrict__ Wg,
                                              const float* __restrict__ bg, int N, int Kmax,
                                              int wid, int lane) {
  const int l15 = lane & 15;
  const int lhi = lane >> 4;
#pragma unroll
  for (int t = 0; t < NCPW; ++t) {
    const int nc = wid * NCPW + t;
    const int col = nc * 16 + l15;
    const float bias = bg[col];
    bf16x8 bfrag[KSTEPS];
#pragma unroll
    for (int ks = 0; ks < KSTEPS; ++ks) {
#pragma unroll
      for (int j = 0; j < 8; ++j) {
        const int k = ks * 32 + lhi * 8 + j;
        float wv = (k < Kmax) ? Wg[(size_t)k * N + col] : 0.0f;
        bfrag[ks][j] = (bf16_t)wv;
      }
    }
#pragma unroll
    for (int m = 0; m < 4; ++m) {
      f32x4 acc = {0.f, 0.f, 0.f, 0.f};
#pragma unroll
      for (int ks = 0; ks < KSTEPS; ++ks) {
        bf16x8 a = ld_frag(inb, m * 16 + l15, ks * 64 + lhi * 16);
        acc = __builtin_amdgcn_mfma_f32_16x16x32_bf16(a, bfrag[ks], acc, 0, 0, 0);
      }
      const int r0 = m * 16 + lhi * 4;
#pragma unroll
      for (int i = 0; i < 4; ++i) {
        float v = acc[i] + bias;
        if (RELU) v = fmaxf(v, 0.f);
        st_act(outb, r0 + i, col, v);
      }
    }
  }
}

__global__ __launch_bounds__(256) void KPlanes_fused_fb(
    const float* __restrict__ xyt, const float* __restrict__ yx, const float* __restrict__ xt,
    const float* __restrict__ yt, const float* __restrict__ fw1, const float* __restrict__ fb1,
    const float* __restrict__ fw2, const float* __restrict__ fb2, const float* __restrict__ w1,
    const float* __restrict__ b1, const float* __restrict__ w2, const float* __restrict__ b2,
    const float* __restrict__ w3, const float* __restrict__ b3, const float* __restrict__ w4,
    const float* __restrict__ b4, const int* __restrict__ fnum_p, float* __restrict__ out) {
  __shared__ unsigned short actA[64 * 256];
  __shared__ unsigned short actB[64 * 256];
  const int tid = threadIdx.x;
  const int lane = tid & 63;
  const int wid = tid >> 6;
  const float fnum = (float)(*fnum_p);
  {
    const int p = tid >> 2;
    const int cgrp = (tid & 3) * 8;
    const int pg = blockIdx.x * 64 + p;
    float x = xyt[pg * 3 + 0];
    float y = xyt[pg * 3 + 1];
    float t = xyt[pg * 3 + 2] / fnum;
    float syx[8], sxt[8], syt[8];
    sample8_f(yx, 540, 960, y, x, cgrp, syx);
    sample8_f(xt, 960, 300, x, t, cgrp, sxt);
    sample8_f(yt, 540, 300, y, t, cgrp, syt);
#pragma unroll
    for (int i = 0; i < 8; ++i) st_act(actA, p, cgrp + i, syx[i] * sxt[i] * syt[i]);
  }
  __syncthreads();
  mfma_layer_fb<1, 1, true>(actA, actB, fw1, fb1, 64, 32, wid, lane);
  __syncthreads();
  mfma_layer_fb<2, 1, true>(actB, actA, fw2, fb2, 64, 64, wid, lane);
  if (tid < 64) {
    const int pg = blockIdx.x * 64 + tid;
    float px = xyt[pg * 3 + 0];
    float py = xyt[pg * 3 + 1];
    float pt = xyt[pg * 3 + 2] / fnum;
    st_act(actA, tid, 64, py);
    st_act(actA, tid, 65, px);
    float sc = 1.f;
#pragma unroll
    for (int j = 0; j < 10; ++j) {
      st_act(actA, tid, 66 + j * 4 + 0, sinf(sc * py));
      st_act(actA, tid, 66 + j * 4 + 1, sinf(sc * px));
      st_act(actA, tid, 66 + j * 4 + 2, cosf(sc * py));
      st_act(actA, tid, 66 + j * 4 + 3, cosf(sc * px));
      sc *= 2.f;
    }
    st_act(actA, tid, 106, pt);
    sc = 1.f;
#pragma unroll
    for (int j = 0; j < 6; ++j) {
      st_act(actA, tid, 107 + j * 2, sinf(sc * pt));
      st_act(actA, tid, 108 + j * 2, cosf(sc * pt));
      sc *= 2.f;
    }
#pragma unroll
    for (int c = 119; c < 128; ++c) st_act(actA, tid, c, 0.f);
  }
  __syncthreads();
  mfma_layer_fb<4, 4, true>(actA, actB, w1, b1, 256, 119, wid, lane);
  __syncthreads();
  mfma_layer_fb<8, 4, true>(actB, actA, w2, b2, 256, 256, wid, lane);
  __syncthreads();
  mfma_layer_fb<8, 4, true>(actA, actB, w3, b3, 256, 256, wid, lane);
  __syncthreads();
  {
    const int p = tid >> 2, c = tid & 3;
    if (c < 3) {
      float acc = 0.f;
#pragma unroll
      for (int k0 = 0; k0 < 256; k0 += 8) {
        int b = swz(p, k0 * 2);
        uint4 u = *reinterpret_cast<const uint4*>(reinterpret_cast<const char*>(actB) + b);
        bf16x8 z = __builtin_bit_cast(bf16x8, u);
#pragma unroll
        for (int j = 0; j < 8; ++j) acc += (float)z[j] * w4[(k0 + j) * 3 + c];
      }
      acc += b4[c];
      out[(size_t)(blockIdx.x * 64 + p) * 3 + c] = 1.f / (1.f + expf(-acc));
    }
  }
}

extern "C" void kernel_launch(void* const* d_in, const int* in_sizes, int n_in, void* d_out,
                              int out_size, void* d_ws, size_t ws_size, hipStream_t stream) {
  const float* xyt = (const float*)d_in[0];
  const float* yx = (const float*)d_in[1];
  const float* xt = (const float*)d_in[2];
  const float* yt = (const float*)d_in[3];
  const float* fw1 = (const float*)d_in[4];
  const float* fb1 = (const float*)d_in[5];
  const float* fw2 = (const float*)d_in[6];
  const float* fb2 = (const float*)d_in[7];
  const float* w1 = (const float*)d_in[8];
  const float* b1 = (const float*)d_in[9];
  const float* w2 = (const float*)d_in[10];
  const float* b2 = (const float*)d_in[11];
  const float* w3 = (const float*)d_in[12];
  const float* b3 = (const float*)d_in[13];
  const float* w4 = (const float*)d_in[14];
  const float* b4 = (const float*)d_in[15];
  const int* fnum = (const int*)d_in[16];
  float* out = (float*)d_out;

  const int hw_yx = 540 * 960, hw_xt = 960 * 300, hw_yt = 540 * 300;
  // fp16 planes: 64B per spatial site
  const size_t plane_bytes = ((size_t)hw_yx + hw_xt + hw_yt) * 64;
  const size_t wfrag_bytes = (size_t)340 * 64 * sizeof(uint4);
  const size_t need = plane_bytes + wfrag_bytes;

  uint4* yx_h = (uint4*)d_ws;
  uint4* xt_h = yx_h + (size_t)hw_yx * 4;
  uint4* yt_h = xt_h + (size_t)hw_xt * 4;
  uint4* wbase = (uint4*)((char*)d_ws + plane_bytes);
  uint4* wf1 = wbase + 0 * 64;
  uint4* wf2 = wbase + 4 * 64;
  uint4* wf3 = wbase + 12 * 64;
  uint4* wf4 = wbase + 76 * 64;
  uint4* wf5 = wbase + 204 * 64;
  uint4* wf6 = wbase + 332 * 64;

  if (ws_size >= need) {
    const int nb_tr = 2025 + 1125 + 633;
    KPlanes_tr3<<<nb_tr, 256, 0, stream>>>(yx, xt, yt, yx_h, xt_h, yt_h);
    KPlanes_packall<<<85, 256, 0, stream>>>(fw1, fw2, w1, w2, w3, w4, wbase);
    KPlanes_fused3<<<NBLK, NTHR, 0, stream>>>(xyt, yx_h, xt_h, yt_h, wf1, fb1, wf2, fb2, wf3, b1,
                                              wf4, b2, wf5, b3, wf6, b4, fnum, out);
  } else {
    KPlanes_fused_fb<<<1048576 / 64, 256, 0, stream>>>(xyt, yx, xt, yt, fw1, fb1, fw2, fb2, w1,
                                                       b1, w2, b2, w3, b3, w4, b4, fnum, out);
  }
}